// Round 10
// baseline (271.405 us; speedup 1.0000x reference)
//
#include <hip/hip_runtime.h>
#include <math.h>

#define B_SZ 4
#define LSEQ 2048
#define DDIM 768
#define NST  16
#define NROW (B_SZ * LSEQ)      // 8192
#define NJ   33                 // 16 B + 16 C + 1 s1

#define NC   64
#define CS   (LSEQ / NC)        // 32
#define DN   (DDIM * NST)       // 12288

// fast exp2: lowers to v_exp_f32
__device__ __forceinline__ float fexp2(float v) { return exp2f(v); }

// ================= projection (R6 config: KSPL=32) =================
#define KSPL 32
#define KCH  (DDIM / KSPL)      // 24

__global__ __launch_bounds__(256) void proj_part_kernel(
    const float* __restrict__ x,
    const float* __restrict__ Wb, const float* __restrict__ Wc,
    const float* __restrict__ W1, float* __restrict__ part)
{
    const int row = blockIdx.x * 256 + threadIdx.x;
    const int s = blockIdx.y;
    const int k0 = s * KCH;

    float4 xv[6];
    const float* xp = x + (size_t)row * DDIM + k0;
    #pragma unroll
    for (int q = 0; q < 6; ++q) xv[q] = *(const float4*)(xp + q * 4);

    float acc[NJ];
    #pragma unroll
    for (int j = 0; j < NJ; ++j) {
        const float* wrow = (j < 16) ? (Wb + j * DDIM)
                          : (j < 32) ? (Wc + (j - 16) * DDIM)
                                     : W1;
        const float* wk = wrow + k0;   // lane-invariant -> s_load stream
        float a = 0.f;
        #pragma unroll
        for (int q = 0; q < 6; ++q) {
            a = fmaf(xv[q].x, wk[q * 4 + 0], a);
            a = fmaf(xv[q].y, wk[q * 4 + 1], a);
            a = fmaf(xv[q].z, wk[q * 4 + 2], a);
            a = fmaf(xv[q].w, wk[q * 4 + 3], a);
        }
        acc[j] = a;
    }
    #pragma unroll
    for (int j = 0; j < NJ; ++j)
        part[((size_t)s * NJ + j) * NROW + row] = acc[j];
}

__global__ __launch_bounds__(256) void proj_reduce_kernel(
    const float* __restrict__ part,
    const float* __restrict__ bb, const float* __restrict__ bc,
    const float* __restrict__ b1,
    float* __restrict__ Bp, float* __restrict__ Cc, float* __restrict__ s1)
{
    const int idx = blockIdx.x * 256 + threadIdx.x;
    if (idx >= NJ * NROW) return;
    const int j = idx / NROW;
    const int row = idx % NROW;
    float a0 = 0.f, a1 = 0.f, a2 = 0.f, a3 = 0.f;
    #pragma unroll 4
    for (int s = 0; s < KSPL; s += 4) {
        a0 += part[((size_t)(s + 0) * NJ + j) * NROW + row];
        a1 += part[((size_t)(s + 1) * NJ + j) * NROW + row];
        a2 += part[((size_t)(s + 2) * NJ + j) * NROW + row];
        a3 += part[((size_t)(s + 3) * NJ + j) * NROW + row];
    }
    const float a = (a0 + a1) + (a2 + a3);
    if (j < 16)      Bp[(size_t)row * NST + j] = a + bb[j];
    else if (j < 32) Cc[(size_t)row * NST + (j - 16)] = a + bc[j - 16];
    else             s1[row] = a + b1[0];
}

// ================= delta precompute =================
// EL[row][d] = softplus(s1[row]*Wd[d]+bd[d]) * log2(e);  DX[row][d] = delta * x[row][d]
#define LOG2E 1.4426950408889634f
__global__ __launch_bounds__(256) void delta_kernel(
    const float* __restrict__ x, const float* __restrict__ s1,
    const float* __restrict__ Wd, const float* __restrict__ bd,
    float* __restrict__ EL, float* __restrict__ DX)
{
    const int d = blockIdx.x * 256 + threadIdx.x;     // gridDim.x = 3
    const int row = blockIdx.y;                        // 8192
    const float sv = s1[row];                          // uniform -> 1 s_load
    const float z = fmaf(sv, Wd[d], bd[d]);
    const float t = __expf(-fabsf(z));
    const float delta = fmaxf(z, 0.f) + __logf(1.f + t);
    const size_t g = (size_t)row * DDIM + d;
    EL[g] = delta * LOG2E;
    DX[g] = delta * x[g];
}

// ================= pass1: chunk-local scan, thread=(b,c,d,n) =================
// grid (48, NC*B_SZ): tid = dl*16+n, d = bx*16+dl
__global__ __launch_bounds__(256) void pass1_kernel(
    const float* __restrict__ A_log,
    const float* __restrict__ Bp, const float* __restrict__ EL,
    const float* __restrict__ DX,
    float* __restrict__ Ssum, float* __restrict__ Q)
{
    const int tid = threadIdx.x;
    const int n = tid & 15;
    const int dl = tid >> 4;
    const int d = blockIdx.x * 16 + dl;
    const int bc = blockIdx.y;                 // b*NC + c
    const int rowbase = (bc >> 6) * LSEQ + (bc & (NC - 1)) * CS;

    const float acn = -__expf(A_log[d * NST + n]);   // coalesced load
    const float* elp = EL + (size_t)rowbase * DDIM + d;
    const float* dxp = DX + (size_t)rowbase * DDIM + d;
    const float* bp  = Bp + (size_t)rowbase * NST + n;

    float h = 0.f, se = 0.f;
    #pragma unroll 8
    for (int l = 0; l < CS; ++l) {
        const float el = elp[(size_t)l * DDIM];
        const float dx = dxp[(size_t)l * DDIM];
        const float bv = bp[(size_t)l * NST];
        const float e = fexp2(el * acn);
        h = fmaf(e, h, dx * bv);
        se += el;
    }
    Q[(size_t)bc * DN + blockIdx.x * 256 + tid] = h;   // r = d*16+n coalesced
    if (n == 0) Ssum[(size_t)bc * DDIM + d] = se;
}

// ================= combine: 4-way split + shfl Kogge-Stone =================
#define CPG (NC / 4)   // 16
__global__ __launch_bounds__(256) void combine_kernel(
    const float* __restrict__ A_log,
    const float* __restrict__ Ssum, const float* __restrict__ Q,
    float* __restrict__ Hin)
{
    const int gidx = blockIdx.x * 256 + threadIdx.x;  // over B*D*N*4
    const int lane = threadIdx.x & 63;
    const int rlow = gidx & 15;
    const int g = (gidx >> 4) & 3;
    const int hi = gidx >> 6;
    const int pairIdx = hi * 16 + rlow;               // [0, B*D*N)
    const int b = pairIdx / DN;
    const int r = pairIdx % DN;
    const int d = r >> 4;
    const float acn = -__expf(A_log[r]);
    const int c0 = g * CPG;

    float eq[CPG], qq[CPG];
    #pragma unroll
    for (int ci = 0; ci < CPG; ++ci) {
        const size_t base = (size_t)(b * NC + c0 + ci);
        eq[ci] = fexp2(acn * Ssum[base * DDIM + d]);   // Ssum already has log2e
        qq[ci] = Q[base * DN + r];
    }
    float E = 1.f, H = 0.f;
    #pragma unroll
    for (int ci = 0; ci < CPG; ++ci) { H = fmaf(eq[ci], H, qq[ci]); E *= eq[ci]; }

    float oE = __shfl_up(E, 16, 64);
    float oH = __shfl_up(H, 16, 64);
    if (lane >= 16) { H = fmaf(E, oH, H); E *= oE; }
    oE = __shfl_up(E, 32, 64);
    oH = __shfl_up(H, 32, 64);
    if (lane >= 32) { H = fmaf(E, oH, H); E *= oE; }

    float hin = __shfl_up(H, 16, 64);   // exclusive
    if (g == 0) hin = 0.f;

    float h = hin;
    #pragma unroll
    for (int ci = 0; ci < CPG; ++ci) {
        const size_t base = (size_t)(b * NC + c0 + ci);
        Hin[base * DN + r] = h;
        h = fmaf(eq[ci], h, qq[ci]);
    }
}

// ================= pass2: final scan + y =================
__global__ __launch_bounds__(256) void pass2_kernel(
    const float* __restrict__ A_log,
    const float* __restrict__ Bp, const float* __restrict__ Cc,
    const float* __restrict__ EL, const float* __restrict__ DX,
    const float* __restrict__ Hin, float* __restrict__ out)
{
    __shared__ float sy[16 * (CS + 1)];        // padded: conflict-free transpose
    const int tid = threadIdx.x;
    const int n = tid & 15;
    const int dl = tid >> 4;
    const int d = blockIdx.x * 16 + dl;
    const int bc = blockIdx.y;
    const int rowbase = (bc >> 6) * LSEQ + (bc & (NC - 1)) * CS;

    const float acn = -__expf(A_log[d * NST + n]);
    const float* elp = EL + (size_t)rowbase * DDIM + d;
    const float* dxp = DX + (size_t)rowbase * DDIM + d;
    const float* bp  = Bp + (size_t)rowbase * NST + n;
    const float* cp  = Cc + (size_t)rowbase * NST + n;

    float h = Hin[(size_t)bc * DN + blockIdx.x * 256 + tid];

    #pragma unroll 8
    for (int l = 0; l < CS; ++l) {
        const float el = elp[(size_t)l * DDIM];
        const float dx = dxp[(size_t)l * DDIM];
        const float bv = bp[(size_t)l * NST];
        const float cv = cp[(size_t)l * NST];
        const float e = fexp2(el * acn);
        h = fmaf(e, h, dx * bv);
        float y = h * cv;
        y += __shfl_xor(y, 1, 16);
        y += __shfl_xor(y, 2, 16);
        y += __shfl_xor(y, 4, 16);
        y += __shfl_xor(y, 8, 16);
        if (n == 0) sy[dl * (CS + 1) + l] = y;
    }
    __syncthreads();
    // flush: 512 outputs, out[(rowbase+l)*DDIM + d0+dl'] coalesced in dl'
    #pragma unroll
    for (int it = 0; it < 2; ++it) {
        const int i = tid + it * 256;
        const int l = i >> 4;
        const int dd = i & 15;
        out[(size_t)(rowbase + l) * DDIM + blockIdx.x * 16 + dd] = sy[dd * (CS + 1) + l];
    }
}

extern "C" void kernel_launch(void* const* d_in, const int* in_sizes, int n_in,
                              void* d_out, int out_size, void* d_ws, size_t ws_size,
                              hipStream_t stream) {
    const float* x     = (const float*)d_in[0];
    const float* A_log = (const float*)d_in[1];
    const float* Wb    = (const float*)d_in[2];
    const float* bb    = (const float*)d_in[3];
    const float* Wc    = (const float*)d_in[4];
    const float* bc    = (const float*)d_in[5];
    const float* W1    = (const float*)d_in[6];
    const float* b1    = (const float*)d_in[7];
    const float* Wd    = (const float*)d_in[8];
    const float* bd    = (const float*)d_in[9];
    float* out = (float*)d_out;

    float* ws = (float*)d_ws;
    const size_t partN = (size_t)KSPL * NJ * NROW;     // 8.65M
    const size_t BpN  = (size_t)NROW * NST;            // 131072
    const size_t s1N  = (size_t)NROW;                  // 8192
    const size_t elN  = (size_t)NROW * DDIM;           // 6.29M
    const size_t sN   = (size_t)B_SZ * NC * DDIM;      // 196608
    const size_t agg  = (size_t)B_SZ * NC * DN;        // 3.15M

    float* part = ws;
    float* Bp   = part + partN;
    float* Cc   = Bp + BpN;
    float* s1   = Cc + BpN;
    float* EL   = s1 + s1N;
    float* DX   = EL + elN;
    float* Ssum = DX + elN;
    float* Q    = Ssum + sN;
    float* Hin  = Q + agg;

    dim3 gproj(NROW / 256, KSPL);
    proj_part_kernel<<<gproj, 256, 0, stream>>>(x, Wb, Wc, W1, part);
    proj_reduce_kernel<<<(NJ * NROW + 255) / 256, 256, 0, stream>>>(part, bb, bc, b1, Bp, Cc, s1);

    delta_kernel<<<dim3(DDIM / 256, NROW), 256, 0, stream>>>(x, s1, Wd, bd, EL, DX);

    dim3 gscan(DDIM / 16, NC * B_SZ);
    pass1_kernel<<<gscan, 256, 0, stream>>>(A_log, Bp, EL, DX, Ssum, Q);

    combine_kernel<<<(B_SZ * DN * 4) / 256, 256, 0, stream>>>(A_log, Ssum, Q, Hin);

    pass2_kernel<<<gscan, 256, 0, stream>>>(A_log, Bp, Cc, EL, DX, Hin, out);
}

// Round 11
// 172.593 us; speedup vs baseline: 1.5725x; 1.5725x over previous
//
#include <hip/hip_runtime.h>
#include <math.h>

#define B_SZ 4
#define LSEQ 2048
#define DDIM 768
#define NST  16
#define NROW (B_SZ * LSEQ)      // 8192
#define NJ   33                 // 16 B + 16 C + 1 s1

#define NC   128
#define CS   (LSEQ / NC)        // 16
#define DN   (DDIM * NST)       // 12288

__device__ __forceinline__ float fexp2(float v) { return exp2f(v); }  // v_exp_f32

// ================= projection (R6 config: KSPL=32) =================
#define KSPL 32
#define KCH  (DDIM / KSPL)      // 24

__global__ __launch_bounds__(256) void proj_part_kernel(
    const float* __restrict__ x,
    const float* __restrict__ Wb, const float* __restrict__ Wc,
    const float* __restrict__ W1, float* __restrict__ part)
{
    const int row = blockIdx.x * 256 + threadIdx.x;
    const int s = blockIdx.y;
    const int k0 = s * KCH;

    float4 xv[6];
    const float* xp = x + (size_t)row * DDIM + k0;
    #pragma unroll
    for (int q = 0; q < 6; ++q) xv[q] = *(const float4*)(xp + q * 4);

    float acc[NJ];
    #pragma unroll
    for (int j = 0; j < NJ; ++j) {
        const float* wrow = (j < 16) ? (Wb + j * DDIM)
                          : (j < 32) ? (Wc + (j - 16) * DDIM)
                                     : W1;
        const float* wk = wrow + k0;   // lane-invariant -> s_load stream
        float a = 0.f;
        #pragma unroll
        for (int q = 0; q < 6; ++q) {
            a = fmaf(xv[q].x, wk[q * 4 + 0], a);
            a = fmaf(xv[q].y, wk[q * 4 + 1], a);
            a = fmaf(xv[q].z, wk[q * 4 + 2], a);
            a = fmaf(xv[q].w, wk[q * 4 + 3], a);
        }
        acc[j] = a;
    }
    #pragma unroll
    for (int j = 0; j < NJ; ++j)
        part[((size_t)s * NJ + j) * NROW + row] = acc[j];
}

__global__ __launch_bounds__(256) void proj_reduce_kernel(
    const float* __restrict__ part,
    const float* __restrict__ bb, const float* __restrict__ bc,
    const float* __restrict__ b1,
    float* __restrict__ Bp, float* __restrict__ Cc, float* __restrict__ s1)
{
    const int idx = blockIdx.x * 256 + threadIdx.x;
    if (idx >= NJ * NROW) return;
    const int j = idx / NROW;
    const int row = idx % NROW;
    float a0 = 0.f, a1 = 0.f, a2 = 0.f, a3 = 0.f;
    #pragma unroll 4
    for (int s = 0; s < KSPL; s += 4) {
        a0 += part[((size_t)(s + 0) * NJ + j) * NROW + row];
        a1 += part[((size_t)(s + 1) * NJ + j) * NROW + row];
        a2 += part[((size_t)(s + 2) * NJ + j) * NROW + row];
        a3 += part[((size_t)(s + 3) * NJ + j) * NROW + row];
    }
    const float a = (a0 + a1) + (a2 + a3);
    if (j < 16)      Bp[(size_t)row * NST + j] = a + bb[j];
    else if (j < 32) Cc[(size_t)row * NST + (j - 16)] = a + bc[j - 16];
    else             s1[row] = a + b1[0];
}

// ================= delta precompute =================
// EL[row][d] = softplus(s1[row]*Wd[d]+bd[d]) * log2(e);  DX[row][d] = delta * x[row][d]
#define LOG2E 1.4426950408889634f
__global__ __launch_bounds__(256) void delta_kernel(
    const float* __restrict__ x, const float* __restrict__ s1,
    const float* __restrict__ Wd, const float* __restrict__ bd,
    float* __restrict__ EL, float* __restrict__ DX)
{
    const int d = blockIdx.x * 256 + threadIdx.x;     // gridDim.x = 3
    const int row = blockIdx.y;                        // 8192
    const float sv = s1[row];                          // uniform -> 1 s_load
    const float z = fmaf(sv, Wd[d], bd[d]);
    const float t = __expf(-fabsf(z));
    const float delta = fmaxf(z, 0.f) + __logf(1.f + t);
    const size_t g = (size_t)row * DDIM + d;
    EL[g] = delta * LOG2E;
    DX[g] = delta * x[g];
}

// ================= scan helpers =================
__device__ __forceinline__ void powers16(float p, float* e) {
    e[0] = p;      e[1] = p * p;      e[2] = e[1] * p;   e[3] = e[1] * e[1];
    e[4] = e[3] * p;  e[5] = e[3] * e[1];  e[6] = e[3] * e[2];  e[7] = e[3] * e[3];
    e[8] = e[7] * p;  e[9] = e[7] * e[1];  e[10] = e[7] * e[2]; e[11] = e[7] * e[3];
    e[12] = e[7] * e[4]; e[13] = e[7] * e[5]; e[14] = e[7] * e[6]; e[15] = e[7] * e[7];
}

__device__ __forceinline__ bool a_structured(const float* acn) {
    bool st = true;
    #pragma unroll
    for (int n = 0; n < NST; ++n)
        st = st && (fabsf(acn[n] - (float)(n + 1) * acn[0]) <= 1e-5f * fabsf(acn[n]));
    return __all(st) != 0;
}

// ================= pass1: chunk-local scan, thread=d, B via LDS =================
// grid (3, NC, B_SZ), block 256
__global__ __launch_bounds__(256) void pass1_kernel(
    const float* __restrict__ A_log,
    const float* __restrict__ Bp, const float* __restrict__ EL,
    const float* __restrict__ DX,
    float* __restrict__ Ssum, float* __restrict__ Q)
{
    __shared__ float sB[CS * NST];             // 1 KB chunk tile
    const int tid = threadIdx.x;
    const int d = blockIdx.x * 256 + tid;
    const int c = blockIdx.y, b = blockIdx.z;
    const int bc = b * NC + c;
    const int rowbase = b * LSEQ + c * CS;

    sB[tid] = Bp[(size_t)rowbase * NST + tid]; // 256 = CS*NST, coalesced
    __syncthreads();

    float acn[NST];
    #pragma unroll
    for (int n = 0; n < NST; ++n) acn[n] = -__expf(A_log[d * NST + n]);
    const float a0 = acn[0];
    const bool structured = a_structured(acn);

    const float* elp = EL + (size_t)rowbase * DDIM + d;   // coalesced over tid
    const float* dxp = DX + (size_t)rowbase * DDIM + d;

    float h[NST];
    #pragma unroll
    for (int n = 0; n < NST; ++n) h[n] = 0.f;
    float se = 0.f;

    if (structured) {
        #pragma unroll 4
        for (int l = 0; l < CS; ++l) {
            const float el = elp[(size_t)l * DDIM];
            const float dx = dxp[(size_t)l * DDIM];
            se += el;
            float e[NST];
            powers16(fexp2(el * a0), e);
            const float* bl = sB + l * NST;    // broadcast ds_read
            #pragma unroll
            for (int n = 0; n < NST; ++n) h[n] = fmaf(e[n], h[n], dx * bl[n]);
        }
    } else {
        #pragma unroll 4
        for (int l = 0; l < CS; ++l) {
            const float el = elp[(size_t)l * DDIM];
            const float dx = dxp[(size_t)l * DDIM];
            se += el;
            float e[NST];
            #pragma unroll
            for (int n = 0; n < NST; ++n) e[n] = fexp2(el * acn[n]);
            const float* bl = sB + l * NST;
            #pragma unroll
            for (int n = 0; n < NST; ++n) h[n] = fmaf(e[n], h[n], dx * bl[n]);
        }
    }
    Ssum[(size_t)bc * DDIM + d] = se;
    const size_t gbase = (size_t)bc * DN + (size_t)d * NST;
    float4* Q4 = (float4*)(Q + gbase);
    #pragma unroll
    for (int q = 0; q < 4; ++q)
        Q4[q] = make_float4(h[q * 4], h[q * 4 + 1], h[q * 4 + 2], h[q * 4 + 3]);
}

// ================= combine: 4-way split + shfl Kogge-Stone (CPG=32) =================
#define CPG (NC / 4)   // 32
__global__ __launch_bounds__(256) void combine_kernel(
    const float* __restrict__ A_log,
    const float* __restrict__ Ssum, const float* __restrict__ Q,
    float* __restrict__ Hin)
{
    const int gidx = blockIdx.x * 256 + threadIdx.x;  // over B*D*N*4
    const int lane = threadIdx.x & 63;
    const int rlow = gidx & 15;
    const int g = (gidx >> 4) & 3;
    const int hi = gidx >> 6;
    const int pairIdx = hi * 16 + rlow;               // [0, B*D*N)
    const int b = pairIdx / DN;
    const int r = pairIdx % DN;
    const int d = r >> 4;
    const float acn = -__expf(A_log[r]);
    const int c0 = g * CPG;

    float eq[CPG], qq[CPG];
    #pragma unroll
    for (int ci = 0; ci < CPG; ++ci) {
        const size_t base = (size_t)(b * NC + c0 + ci);
        eq[ci] = fexp2(acn * Ssum[base * DDIM + d]);   // Ssum already carries log2e
        qq[ci] = Q[base * DN + r];
    }
    float E = 1.f, H = 0.f;
    #pragma unroll
    for (int ci = 0; ci < CPG; ++ci) { H = fmaf(eq[ci], H, qq[ci]); E *= eq[ci]; }

    float oE = __shfl_up(E, 16, 64);
    float oH = __shfl_up(H, 16, 64);
    if (lane >= 16) { H = fmaf(E, oH, H); E *= oE; }
    oE = __shfl_up(E, 32, 64);
    oH = __shfl_up(H, 32, 64);
    if (lane >= 32) { H = fmaf(E, oH, H); E *= oE; }

    float hin = __shfl_up(H, 16, 64);   // exclusive
    if (g == 0) hin = 0.f;

    float h = hin;
    #pragma unroll
    for (int ci = 0; ci < CPG; ++ci) {
        const size_t base = (size_t)(b * NC + c0 + ci);
        Hin[base * DN + r] = h;
        h = fmaf(eq[ci], h, qq[ci]);
    }
}

// ================= pass2: final scan + y, thread=d, B/C via LDS =================
__global__ __launch_bounds__(256) void pass2_kernel(
    const float* __restrict__ A_log,
    const float* __restrict__ Bp, const float* __restrict__ Cc,
    const float* __restrict__ EL, const float* __restrict__ DX,
    const float* __restrict__ Hin, float* __restrict__ out)
{
    __shared__ float sB[CS * NST];
    __shared__ float sC[CS * NST];
    const int tid = threadIdx.x;
    const int d = blockIdx.x * 256 + tid;
    const int c = blockIdx.y, b = blockIdx.z;
    const int bc = b * NC + c;
    const int rowbase = b * LSEQ + c * CS;

    sB[tid] = Bp[(size_t)rowbase * NST + tid];
    sC[tid] = Cc[(size_t)rowbase * NST + tid];
    __syncthreads();

    float acn[NST];
    #pragma unroll
    for (int n = 0; n < NST; ++n) acn[n] = -__expf(A_log[d * NST + n]);
    const float a0 = acn[0];
    const bool structured = a_structured(acn);

    const float* elp = EL + (size_t)rowbase * DDIM + d;
    const float* dxp = DX + (size_t)rowbase * DDIM + d;
    float* yp = out + (size_t)rowbase * DDIM + d;

    float h[NST];
    const size_t gbase = (size_t)bc * DN + (size_t)d * NST;
    const float4* H4 = (const float4*)(Hin + gbase);
    #pragma unroll
    for (int q = 0; q < 4; ++q) {
        const float4 hv = H4[q];
        h[q * 4] = hv.x; h[q * 4 + 1] = hv.y; h[q * 4 + 2] = hv.z; h[q * 4 + 3] = hv.w;
    }

    if (structured) {
        #pragma unroll 4
        for (int l = 0; l < CS; ++l) {
            const float el = elp[(size_t)l * DDIM];
            const float dx = dxp[(size_t)l * DDIM];
            float e[NST];
            powers16(fexp2(el * a0), e);
            const float* bl = sB + l * NST;
            const float* cl = sC + l * NST;
            float y0 = 0.f, y1 = 0.f, y2 = 0.f, y3 = 0.f;
            #pragma unroll
            for (int q = 0; q < 4; ++q) {
                h[q*4+0] = fmaf(e[q*4+0], h[q*4+0], dx * bl[q*4+0]);
                h[q*4+1] = fmaf(e[q*4+1], h[q*4+1], dx * bl[q*4+1]);
                h[q*4+2] = fmaf(e[q*4+2], h[q*4+2], dx * bl[q*4+2]);
                h[q*4+3] = fmaf(e[q*4+3], h[q*4+3], dx * bl[q*4+3]);
            }
            #pragma unroll
            for (int q = 0; q < 4; ++q) {
                y0 = fmaf(h[q*4+0], cl[q*4+0], y0);
                y1 = fmaf(h[q*4+1], cl[q*4+1], y1);
                y2 = fmaf(h[q*4+2], cl[q*4+2], y2);
                y3 = fmaf(h[q*4+3], cl[q*4+3], y3);
            }
            yp[(size_t)l * DDIM] = (y0 + y1) + (y2 + y3);   // coalesced over tid
        }
    } else {
        #pragma unroll 4
        for (int l = 0; l < CS; ++l) {
            const float el = elp[(size_t)l * DDIM];
            const float dx = dxp[(size_t)l * DDIM];
            float e[NST];
            #pragma unroll
            for (int n = 0; n < NST; ++n) e[n] = fexp2(el * acn[n]);
            const float* bl = sB + l * NST;
            const float* cl = sC + l * NST;
            float y0 = 0.f, y1 = 0.f, y2 = 0.f, y3 = 0.f;
            #pragma unroll
            for (int n = 0; n < NST; ++n) h[n] = fmaf(e[n], h[n], dx * bl[n]);
            #pragma unroll
            for (int q = 0; q < 4; ++q) {
                y0 = fmaf(h[q*4+0], cl[q*4+0], y0);
                y1 = fmaf(h[q*4+1], cl[q*4+1], y1);
                y2 = fmaf(h[q*4+2], cl[q*4+2], y2);
                y3 = fmaf(h[q*4+3], cl[q*4+3], y3);
            }
            yp[(size_t)l * DDIM] = (y0 + y1) + (y2 + y3);
        }
    }
}

extern "C" void kernel_launch(void* const* d_in, const int* in_sizes, int n_in,
                              void* d_out, int out_size, void* d_ws, size_t ws_size,
                              hipStream_t stream) {
    const float* x     = (const float*)d_in[0];
    const float* A_log = (const float*)d_in[1];
    const float* Wb    = (const float*)d_in[2];
    const float* bb    = (const float*)d_in[3];
    const float* Wc    = (const float*)d_in[4];
    const float* bc    = (const float*)d_in[5];
    const float* W1    = (const float*)d_in[6];
    const float* b1    = (const float*)d_in[7];
    const float* Wd    = (const float*)d_in[8];
    const float* bd    = (const float*)d_in[9];
    float* out = (float*)d_out;

    float* ws = (float*)d_ws;
    const size_t partN = (size_t)KSPL * NJ * NROW;     // 8.65M
    const size_t BpN  = (size_t)NROW * NST;            // 131072
    const size_t s1N  = (size_t)NROW;                  // 8192
    const size_t elN  = (size_t)NROW * DDIM;           // 6.29M
    const size_t sN   = (size_t)B_SZ * NC * DDIM;      // 393216
    const size_t agg  = (size_t)B_SZ * NC * DN;        // 6.29M

    float* part = ws;
    float* Bp   = part + partN;
    float* Cc   = Bp + BpN;
    float* s1   = Cc + BpN;
    float* EL   = s1 + s1N;
    float* DX   = EL + elN;
    float* Ssum = DX + elN;
    float* Q    = Ssum + sN;
    float* Hin  = Q + agg;

    dim3 gproj(NROW / 256, KSPL);
    proj_part_kernel<<<gproj, 256, 0, stream>>>(x, Wb, Wc, W1, part);
    proj_reduce_kernel<<<(NJ * NROW + 255) / 256, 256, 0, stream>>>(part, bb, bc, b1, Bp, Cc, s1);

    delta_kernel<<<dim3(DDIM / 256, NROW), 256, 0, stream>>>(x, s1, Wd, bd, EL, DX);

    dim3 gscan(DDIM / 256, NC, B_SZ);
    pass1_kernel<<<gscan, 256, 0, stream>>>(A_log, Bp, EL, DX, Ssum, Q);

    combine_kernel<<<(B_SZ * DN * 4) / 256, 256, 0, stream>>>(A_log, Ssum, Q, Hin);

    pass2_kernel<<<gscan, 256, 0, stream>>>(A_log, Bp, Cc, EL, DX, Hin, out);
}